// Round 7
// baseline (173.837 us; speedup 1.0000x reference)
//
#include <hip/hip_runtime.h>
#include <stdint.h>

#define NN 4096
#define MM 8192
#define DD 512
#define KT 8  // 512 / BK, BK = 64

typedef __bf16 bf16x8 __attribute__((ext_vector_type(8)));
typedef __bf16 bf16x4 __attribute__((ext_vector_type(4)));
typedef float f32x4 __attribute__((ext_vector_type(4)));
typedef float f32x16 __attribute__((ext_vector_type(16)));

__device__ __forceinline__ void load_lds16(const void* g, void* l) {
  // async global -> LDS, 16B/lane; LDS dest must be wave-uniform base + lane*16.
  __builtin_amdgcn_global_load_lds(
      (const __attribute__((address_space(1))) unsigned int*)g,
      (__attribute__((address_space(3))) unsigned int*)l, 16, 0, 0);
}

// VALU-pipe partial reduction: x += rotate_within_row16(x, k). No LDS traffic.
template <int CTRL>
__device__ __forceinline__ float dpp_radd(float x) {
  int xi = __float_as_int(x);
  int mv = __builtin_amdgcn_update_dpp(xi, xi, CTRL, 0xF, 0xF, false);
  return x + __int_as_float(mv);
}
// One LDS-network op: add lane^16 partner (within each 32-lane group).
__device__ __forceinline__ float swz_add_xor16(float x) {
  int sv = __builtin_amdgcn_ds_swizzle(__float_as_int(x), 0x401F);
  return x + __int_as_float(sv);
}

// 4 rows per 256-thread block, one wave per row. Fully-coalesced f32x4 loads,
// bf16x4 stores, exact fp32 row-norm, and out[]=IC init folded in.
__global__ __launch_bounds__(256) void convert_norm_kernel(
    const float* __restrict__ X, const float* __restrict__ SV,
    __bf16* __restrict__ Xb, __bf16* __restrict__ SVb,
    float* __restrict__ x2, float* __restrict__ sv2,
    float* __restrict__ out, const float* __restrict__ IC) {
  int wid = blockIdx.x * 4 + (threadIdx.x >> 6);
  int lane = threadIdx.x & 63;
  const float* src;
  __bf16* dst;
  float* nrm;
  if (wid < NN) {
    src = X + (size_t)wid * DD;
    dst = Xb + (size_t)wid * DD;
    nrm = x2 + wid;
    if (lane == 0) out[wid] = IC[0];
  } else {
    int r = wid - NN;
    src = SV + (size_t)r * DD;
    dst = SVb + (size_t)r * DD;
    nrm = sv2 + r;
  }
  const f32x4* s = (const f32x4*)src;
  f32x4 a = s[lane];
  f32x4 b = s[lane + 64];
  float sum = a.x * a.x + a.y * a.y + a.z * a.z + a.w * a.w +
              b.x * b.x + b.y * b.y + b.z * b.z + b.w * b.w;
  bf16x4 ca = {(__bf16)a.x, (__bf16)a.y, (__bf16)a.z, (__bf16)a.w};
  bf16x4 cb = {(__bf16)b.x, (__bf16)b.y, (__bf16)b.z, (__bf16)b.w};
  *(bf16x4*)(dst + 4 * lane) = ca;
  *(bf16x4*)(dst + 256 + 4 * lane) = cb;
#pragma unroll
  for (int m = 32; m >= 1; m >>= 1) sum += __shfl_xor(sum, m, 64);
  if (lane == 0) *nrm = sum;
}

// R4 structure (proven best): 128x128 tile, BK=64, 4 waves (2x2), each wave
// 64x64 via 2x2 of mfma_f32_32x32x16_bf16. Single 32 KB LDS buffer ->
// 4 blocks/CU; cross-block wave overlap hides staging latency.
// NEW vs R4:
//  (1) XCD-aware tile remap: linear id & 7 selects an 8-way partition of the
//      (32 x 64) tile grid into 16x16-tile regions -> per-XCD L2 working set
//      = 2 MB A + 2 MB B = 4 MB (fits) -> barrier drains see L2-hit latency.
//  (2) Epilogue reduction via DPP row_ror (VALU) + one ds_swizzle xor16,
//      replacing the 5-level __shfl_xor LDS tree (was 4.19M conflict cycles).
__global__ __launch_bounds__(256, 4) void rbf_gemm_kernel(
    const bf16x8* __restrict__ Xb, const bf16x8* __restrict__ SVb,
    const float* __restrict__ x2, const float* __restrict__ sv2,
    const float* __restrict__ DC, const float* __restrict__ gamma_p,
    float* __restrict__ out) {
  __shared__ bf16x8 As[1024];  // 16 KB
  __shared__ bf16x8 Bs[1024];  // 16 KB

  const int t = threadIdx.x;
  const int lane = t & 63;
  const int wave = t >> 6;

  // ---- XCD-aware tile remap (grid = 32 x 64 tiles, 2048 blocks) ----
  const int id = blockIdx.x + (int)gridDim.x * blockIdx.y;
  const int xcd = id & 7;
  const int w = id >> 3;                  // 0..255 within-XCD index
  const int bx = (w >> 4) + (xcd & 1) * 16;   // 0..31 (n-tile)
  const int by = (w & 15) + (xcd >> 1) * 16;  // 0..63 (m-tile)
  const int n0 = bx * 128;
  const int m0 = by * 128;

  const int wave_m = wave & 1;   // m-dir of C
  const int wave_n = wave >> 1;  // n-dir of C
  const int l31 = lane & 31;
  const int lhi = lane >> 5;

  // staging decomposition: chunk c_it = it*256 + t
  const int srow = t >> 3;            // row contribution for it=0 (rows 0..31)
  const int sslot = t & 7;

  f32x16 acc[2][2];
#pragma unroll
  for (int i = 0; i < 2; ++i)
#pragma unroll
    for (int j = 0; j < 2; ++j)
#pragma unroll
      for (int r = 0; r < 16; ++r) acc[i][j][r] = 0.0f;

  for (int kt = 0; kt < KT; ++kt) {
    // ---- cooperative staging: 4 instrs A + 4 instrs B per thread ----
#pragma unroll
    for (int it = 0; it < 4; ++it) {
      const int c = it * 256 + t;
      const int row = it * 32 + srow;
      const int kg = sslot ^ (row & 7);
      load_lds16(Xb + (size_t)(n0 + row) * 64 + kt * 8 + kg, &As[c]);
      load_lds16(SVb + (size_t)(m0 + row) * 64 + kt * 8 + kg, &Bs[c]);
    }
    __syncthreads();
    // ---- compute ----
#pragma unroll
    for (int ks = 0; ks < 4; ++ks) {
      const int kc = ks * 2 + lhi;        // k-chunk 0..7
      const int sw = kc ^ (l31 & 7);
      const int ra = (wave_n * 64 + l31) * 8;
      const int rb = (wave_m * 64 + l31) * 8;
      bf16x8 af0 = As[ra + sw];
      bf16x8 af1 = As[ra + 256 + sw];  // +32 rows
      bf16x8 bf0 = Bs[rb + sw];
      bf16x8 bf1 = Bs[rb + 256 + sw];
      acc[0][0] = __builtin_amdgcn_mfma_f32_32x32x16_bf16(af0, bf0, acc[0][0], 0, 0, 0);
      acc[0][1] = __builtin_amdgcn_mfma_f32_32x32x16_bf16(af0, bf1, acc[0][1], 0, 0, 0);
      acc[1][0] = __builtin_amdgcn_mfma_f32_32x32x16_bf16(af1, bf0, acc[1][0], 0, 0, 0);
      acc[1][1] = __builtin_amdgcn_mfma_f32_32x32x16_bf16(af1, bf1, acc[1][1], 0, 0, 0);
    }
    __syncthreads();
  }

  // ---- epilogue (no barriers) ----
  const float g = gamma_p[0];
  const float c2 = g * 1.4426950408889634f;  // gamma * log2(e)

  float sv2v[2], dcv[2];
  const int colb = m0 + wave_m * 64 + l31;
  sv2v[0] = sv2[colb];
  dcv[0] = DC[colb];
  sv2v[1] = sv2[colb + 32];
  dcv[1] = DC[colb + 32];

#pragma unroll
  for (int i = 0; i < 2; ++i) {
    // C row = rowb + 8*g4 + r2, where reg = g4*4 + r2
    const int rowb = n0 + wave_n * 64 + i * 32 + 4 * lhi;
    float val[16];
#pragma unroll
    for (int g4 = 0; g4 < 4; ++g4) {
      f32x4 xv = *(const f32x4*)(x2 + rowb + 8 * g4);
#pragma unroll
      for (int r2 = 0; r2 < 4; ++r2) {
        const int reg = g4 * 4 + r2;
        float v = 0.0f;
#pragma unroll
        for (int j = 0; j < 2; ++j) {
          float d2 = xv[r2] + sv2v[j] - 2.0f * acc[i][j][reg];
          d2 = fmaxf(d2, 0.0f);
          v += exp2f(-c2 * d2) * dcv[j];
        }
        val[reg] = v;
      }
    }
    // reduce over 32 column-lanes: 4 DPP row-rotations (VALU) cover the
    // 16-lane rows, one ds_swizzle xor16 merges the two rows of each half.
#pragma unroll
    for (int reg = 0; reg < 16; ++reg) {
      float v = val[reg];
      v = dpp_radd<0x121>(v);  // row_ror:1
      v = dpp_radd<0x122>(v);  // row_ror:2
      v = dpp_radd<0x124>(v);  // row_ror:4
      v = dpp_radd<0x128>(v);  // row_ror:8
      val[reg] = swz_add_xor16(v);
    }
    if (l31 == 0) {
#pragma unroll
      for (int g4 = 0; g4 < 4; ++g4)
#pragma unroll
        for (int r2 = 0; r2 < 4; ++r2)
          atomicAdd(&out[rowb + 8 * g4 + r2], val[g4 * 4 + r2]);
    }
  }
}

extern "C" void kernel_launch(void* const* d_in, const int* in_sizes, int n_in,
                              void* d_out, int out_size, void* d_ws, size_t ws_size,
                              hipStream_t stream) {
  const float* X = (const float*)d_in[0];
  const float* SV = (const float*)d_in[1];
  const float* DC = (const float*)d_in[2];
  const float* IC = (const float*)d_in[3];
  const float* gamma = (const float*)d_in[4];
  float* out = (float*)d_out;

  char* ws = (char*)d_ws;
  __bf16* Xb = (__bf16*)ws;                                   // 4 MB
  __bf16* SVb = (__bf16*)(ws + (size_t)NN * DD * 2);          // 8 MB
  float* x2 = (float*)(ws + (size_t)(NN + MM) * DD * 2);      // 16 KB
  float* sv2 = x2 + NN;                                       // 32 KB

  convert_norm_kernel<<<(NN + MM) / 4, 256, 0, stream>>>(X, SV, Xb, SVb, x2, sv2, out, IC);
  dim3 grid(NN / 128, MM / 128);
  rbf_gemm_kernel<<<grid, 256, 0, stream>>>((const bf16x8*)Xb, (const bf16x8*)SVb,
                                            x2, sv2, DC, gamma, out);
}

// Round 8
// 135.994 us; speedup vs baseline: 1.2783x; 1.2783x over previous
//
#include <hip/hip_runtime.h>
#include <stdint.h>

#define NN 4096
#define MM 8192
#define DD 512
#define KTN 16  // 512 / BK, BK = 32

typedef __bf16 bf16x8 __attribute__((ext_vector_type(8)));
typedef __bf16 bf16x4 __attribute__((ext_vector_type(4)));
typedef float f32x4 __attribute__((ext_vector_type(4)));
typedef float f32x16 __attribute__((ext_vector_type(16)));

__device__ __forceinline__ void load_lds16(const void* g, void* l) {
  // async global -> LDS, 16B/lane; LDS dest must be wave-uniform base + lane*16.
  __builtin_amdgcn_global_load_lds(
      (const __attribute__((address_space(1))) unsigned int*)g,
      (__attribute__((address_space(3))) unsigned int*)l, 16, 0, 0);
}

// VALU-pipe partial reduction (verified correct in R7): x += rot16(x, k).
template <int CTRL>
__device__ __forceinline__ float dpp_radd(float x) {
  int xi = __float_as_int(x);
  int mv = __builtin_amdgcn_update_dpp(xi, xi, CTRL, 0xF, 0xF, false);
  return x + __int_as_float(mv);
}
__device__ __forceinline__ float swz_add_xor16(float x) {
  int sv = __builtin_amdgcn_ds_swizzle(__float_as_int(x), 0x401F);
  return x + __int_as_float(sv);
}

// 4 rows per 256-thread block, one wave per row. Fully-coalesced f32x4 loads,
// bf16x4 stores, exact fp32 row-norm, and out[]=IC init folded in.
__global__ __launch_bounds__(256) void convert_norm_kernel(
    const float* __restrict__ X, const float* __restrict__ SV,
    __bf16* __restrict__ Xb, __bf16* __restrict__ SVb,
    float* __restrict__ x2, float* __restrict__ sv2,
    float* __restrict__ out, const float* __restrict__ IC) {
  int wid = blockIdx.x * 4 + (threadIdx.x >> 6);
  int lane = threadIdx.x & 63;
  const float* src;
  __bf16* dst;
  float* nrm;
  if (wid < NN) {
    src = X + (size_t)wid * DD;
    dst = Xb + (size_t)wid * DD;
    nrm = x2 + wid;
    if (lane == 0) out[wid] = IC[0];
  } else {
    int r = wid - NN;
    src = SV + (size_t)r * DD;
    dst = SVb + (size_t)r * DD;
    nrm = sv2 + r;
  }
  const f32x4* s = (const f32x4*)src;
  f32x4 a = s[lane];
  f32x4 b = s[lane + 64];
  float sum = a.x * a.x + a.y * a.y + a.z * a.z + a.w * a.w +
              b.x * b.x + b.y * b.y + b.z * b.z + b.w * b.w;
  bf16x4 ca = {(__bf16)a.x, (__bf16)a.y, (__bf16)a.z, (__bf16)a.w};
  bf16x4 cb = {(__bf16)b.x, (__bf16)b.y, (__bf16)b.z, (__bf16)b.w};
  *(bf16x4*)(dst + 4 * lane) = ca;
  *(bf16x4*)(dst + 256 + 4 * lane) = cb;
#pragma unroll
  for (int m = 32; m >= 1; m >>= 1) sum += __shfl_xor(sum, m, 64);
  if (lane == 0) *nrm = sum;
}

// R4 config (128x128 tile, 4 waves 2x2, 64x64/wave via 2x2 mfma_32x32x16,
// 32 KB LDS, 4 blocks/CU) + BK=32 DOUBLE-buffer so the per-kt barrier's
// vmcnt(0) drain waits on loads issued a full compute phase earlier
// (stage(kt+1, buf^1) BEFORE compute(kt, buf); one barrier per kt).
//
// Swizzle (verified conflict-free via R6 counter): per buffer/matrix,
// 128 rows x 4 chunks of 16 B, P(row,kg) = row*4 + (kg ^ ((row>>1)&3)).
// Note (row+32) has the same swizzle term (32 ≡ 0 mod 4 after >>1&3).
// Epilogue: DPP row_ror reduction (VALU pipe) + one ds_swizzle xor16 —
// frees ~25k cy/CU of LDS-network ops vs the __shfl_xor tree (R7-verified).
__global__ __launch_bounds__(256, 4) void rbf_gemm_kernel(
    const bf16x8* __restrict__ Xb, const bf16x8* __restrict__ SVb,
    const float* __restrict__ x2, const float* __restrict__ sv2,
    const float* __restrict__ DC, const float* __restrict__ gamma_p,
    float* __restrict__ out) {
  __shared__ bf16x8 As[2][512];  // 2 x 8 KB
  __shared__ bf16x8 Bs[2][512];  // 2 x 8 KB

  const int t = threadIdx.x;
  const int lane = t & 63;
  const int wave = t >> 6;
  const int n0 = blockIdx.x * 128;
  const int m0 = blockIdx.y * 128;

  const int wave_m = wave & 1;   // m-dir of C
  const int wave_n = wave >> 1;  // n-dir of C
  const int l31 = lane & 31;
  const int lhi = lane >> 5;

  // staging: chunks c0 = t, c1 = t + 256 (512 chunks per matrix per kt)
  const int c0 = t;
  const int c1 = t + 256;
  const int r0 = c0 >> 2, k0 = (c0 & 3) ^ ((r0 >> 1) & 3);
  const int r1 = c1 >> 2, k1 = (c1 & 3) ^ ((r1 >> 1) & 3);
  const size_t gA0 = (size_t)(n0 + r0) * 64 + k0;  // chunk index into Xb
  const size_t gA1 = (size_t)(n0 + r1) * 64 + k1;
  const size_t gB0 = (size_t)(m0 + r0) * 64 + k0;
  const size_t gB1 = (size_t)(m0 + r1) * 64 + k1;

  // fragment read bases (chunk index) + swizzle term (same for row and row+32)
  const int ra4 = (wave_n * 64 + l31) * 4;
  const int rb4 = (wave_m * 64 + l31) * 4;
  const int swb = (l31 >> 1) & 3;

  f32x16 acc[2][2];
#pragma unroll
  for (int i = 0; i < 2; ++i)
#pragma unroll
    for (int j = 0; j < 2; ++j)
#pragma unroll
      for (int r = 0; r < 16; ++r) acc[i][j][r] = 0.0f;

  // prologue: stage kt=0 into buffer 0
  load_lds16(Xb + gA0, &As[0][c0]);
  load_lds16(Xb + gA1, &As[0][c1]);
  load_lds16(SVb + gB0, &Bs[0][c0]);
  load_lds16(SVb + gB1, &Bs[0][c1]);
  __syncthreads();

#pragma unroll
  for (int kt = 0; kt < KTN; ++kt) {
    const int cur = kt & 1;
    const int nxt = cur ^ 1;
    // stage kt+1 into the other buffer (in flight during compute below)
    if (kt + 1 < KTN) {
      const size_t ko = (size_t)(kt + 1) * 4;
      load_lds16(Xb + gA0 + ko, &As[nxt][c0]);
      load_lds16(Xb + gA1 + ko, &As[nxt][c1]);
      load_lds16(SVb + gB0 + ko, &Bs[nxt][c0]);
      load_lds16(SVb + gB1 + ko, &Bs[nxt][c1]);
    }
    // compute kt from buf[cur]
#pragma unroll
    for (int ks = 0; ks < 2; ++ks) {
      const int kc = ks * 2 + lhi;  // chunk 0..3
      const int sw = kc ^ swb;
      bf16x8 af0 = As[cur][ra4 + sw];
      bf16x8 af1 = As[cur][ra4 + 128 + sw];  // +32 rows
      bf16x8 bf0 = Bs[cur][rb4 + sw];
      bf16x8 bf1 = Bs[cur][rb4 + 128 + sw];
      acc[0][0] = __builtin_amdgcn_mfma_f32_32x32x16_bf16(af0, bf0, acc[0][0], 0, 0, 0);
      acc[0][1] = __builtin_amdgcn_mfma_f32_32x32x16_bf16(af0, bf1, acc[0][1], 0, 0, 0);
      acc[1][0] = __builtin_amdgcn_mfma_f32_32x32x16_bf16(af1, bf0, acc[1][0], 0, 0, 0);
      acc[1][1] = __builtin_amdgcn_mfma_f32_32x32x16_bf16(af1, bf1, acc[1][1], 0, 0, 0);
    }
    __syncthreads();
  }

  // ---- epilogue (no barriers) ----
  const float g = gamma_p[0];
  const float c2 = g * 1.4426950408889634f;  // gamma * log2(e)

  float sv2v[2], dcv[2];
  const int colb = m0 + wave_m * 64 + l31;
  sv2v[0] = sv2[colb];
  dcv[0] = DC[colb];
  sv2v[1] = sv2[colb + 32];
  dcv[1] = DC[colb + 32];

#pragma unroll
  for (int i = 0; i < 2; ++i) {
    // C row = rowb + 8*g4 + r2, where reg = g4*4 + r2
    const int rowb = n0 + wave_n * 64 + i * 32 + 4 * lhi;
    float val[16];
#pragma unroll
    for (int g4 = 0; g4 < 4; ++g4) {
      f32x4 xv = *(const f32x4*)(x2 + rowb + 8 * g4);
#pragma unroll
      for (int r2 = 0; r2 < 4; ++r2) {
        const int reg = g4 * 4 + r2;
        float v = 0.0f;
#pragma unroll
        for (int j = 0; j < 2; ++j) {
          float d2 = xv[r2] + sv2v[j] - 2.0f * acc[i][j][reg];
          d2 = fmaxf(d2, 0.0f);
          v += exp2f(-c2 * d2) * dcv[j];
        }
        val[reg] = v;
      }
    }
    // reduce over 32 column-lanes: 4 DPP row-rotations (VALU pipe) + one
    // ds_swizzle xor16 (verified correct in R7).
#pragma unroll
    for (int reg = 0; reg < 16; ++reg) {
      float v = val[reg];
      v = dpp_radd<0x121>(v);  // row_ror:1
      v = dpp_radd<0x122>(v);  // row_ror:2
      v = dpp_radd<0x124>(v);  // row_ror:4
      v = dpp_radd<0x128>(v);  // row_ror:8
      val[reg] = swz_add_xor16(v);
    }
    if (l31 == 0) {
#pragma unroll
      for (int g4 = 0; g4 < 4; ++g4)
#pragma unroll
        for (int r2 = 0; r2 < 4; ++r2)
          atomicAdd(&out[rowb + 8 * g4 + r2], val[g4 * 4 + r2]);
    }
  }
}

extern "C" void kernel_launch(void* const* d_in, const int* in_sizes, int n_in,
                              void* d_out, int out_size, void* d_ws, size_t ws_size,
                              hipStream_t stream) {
  const float* X = (const float*)d_in[0];
  const float* SV = (const float*)d_in[1];
  const float* DC = (const float*)d_in[2];
  const float* IC = (const float*)d_in[3];
  const float* gamma = (const float*)d_in[4];
  float* out = (float*)d_out;

  char* ws = (char*)d_ws;
  __bf16* Xb = (__bf16*)ws;                                   // 4 MB
  __bf16* SVb = (__bf16*)(ws + (size_t)NN * DD * 2);          // 8 MB
  float* x2 = (float*)(ws + (size_t)(NN + MM) * DD * 2);      // 16 KB
  float* sv2 = x2 + NN;                                       // 32 KB

  convert_norm_kernel<<<(NN + MM) / 4, 256, 0, stream>>>(X, SV, Xb, SVb, x2, sv2, out, IC);
  dim3 grid(NN / 128, MM / 128);
  rbf_gemm_kernel<<<grid, 256, 0, stream>>>((const bf16x8*)Xb, (const bf16x8*)SVb,
                                            x2, sv2, DC, gamma, out);
}